// Round 3
// baseline (766.828 us; speedup 1.0000x reference)
//
#include <hip/hip_runtime.h>
#include <hip/hip_cooperative_groups.h>
#include <math.h>

namespace cg = cooperative_groups;

#define NPIX  4194304          // 16*512*512
#define HW    262144           // 512*512
#define NCH   19
#define KSEL  262144u          // N_MIN
#define IGN   1
#define THRESH_F 0.35667494393873245f   // -log(0.7)

#define GBLK  512              // needs only 2 blocks/CU on 256 CUs (validated by coop launch)
#define NPASS 8                // 512 blk x 256 thr x 4 px x 8 passes = NPIX

// ---------------------------------------------------------------------------
// Parallel "find bin containing kth largest" over an nbins (<=2048) histogram.
// res[0] = bin B, res[1] = count strictly above bin B. All 256 threads.
// sh: >= nbins u32 shared scratch; ss: 256 u32 shared scratch.
// ---------------------------------------------------------------------------
__device__ __forceinline__ void select_from_hist(
    const unsigned int* __restrict__ gh, int nbins, unsigned int need,
    int* res, unsigned int* sh, unsigned int* ss)
{
    const int tid = threadIdx.x;
    for (int i = tid; i < nbins; i += 256) sh[i] = gh[i];
    __syncthreads();
    const int per = nbins >> 8;
    const int base = tid * per;
    unsigned int p = 0;
    for (int i = 0; i < per; ++i) p += sh[base + i];
    ss[tid] = p;
    __syncthreads();
    for (int off = 1; off < 256; off <<= 1) {
        unsigned int add = (tid + off < 256) ? ss[tid + off] : 0u;
        __syncthreads();
        ss[tid] += add;
        __syncthreads();
    }
    unsigned int Sme   = ss[tid];
    unsigned int Snext = (tid < 255) ? ss[tid + 1] : 0u;
    if (Sme >= need && Snext < need) {
        unsigned int above = Snext;
        int bin = base;
        for (int b = base + per - 1; b >= base; --b) {
            unsigned int c = sh[b];
            if (above + c >= need) { bin = b; break; }
            above += c;
        }
        res[0] = bin; res[1] = (int)above;
    }
    if (tid == 0 && ss[0] < need) { res[0] = 0; res[1] = 0; }
    __syncthreads();
}

// ---------------------------------------------------------------------------
// Cooperative mega-kernel:
//   phase1 loss+hist1 -> grid.sync -> phase2 hist2 -> grid.sync ->
//   phase3 hist3 -> grid.sync -> phase4 (block 0) final.
// Losses live ONLY in LDS ([q][256] layout: bank = tid%32, 2 lanes/bank = free).
// ---------------------------------------------------------------------------
__global__ __launch_bounds__(256, 2) void k_mega(
    const float* __restrict__ logits, const int* __restrict__ labels,
    unsigned int* __restrict__ hist1, unsigned int* __restrict__ hist2,
    unsigned int* __restrict__ hist3,
    float* __restrict__ psum, unsigned int* __restrict__ pcnt,
    double* __restrict__ ghi1, double* __restrict__ ghi2,
    float* __restrict__ out)
{
    __shared__ float        lls[NPASS * 4 * 256];   // 32 KiB: this block's losses
    __shared__ unsigned int lh[2048];               // hist accum / select sh / h3
    __shared__ unsigned int ssum[256];              // select scan / c_suf
    __shared__ double       sdbl[256];              // reductions / s_suf
    __shared__ int          res[2];
    __shared__ float        s_sumw[4];
    __shared__ unsigned int s_cntw[4];

    const int tid = threadIdx.x;
    const int bid = blockIdx.x;
    cg::grid_group grid = cg::this_grid();

    for (int i = tid; i < 2048; i += 256) lh[i] = 0u;
    __syncthreads();

    // ---------------- phase 1: CE losses + hist1 + branch-1 partials -------
    float lsum = 0.f;
    unsigned int lcnt = 0u;

    #pragma unroll 1
    for (int k = 0; k < NPASS; ++k) {
        const int t = k * GBLK + bid;               // 1024-px tile; 256 tiles/image
        const float* base = logits + (size_t)(t >> 8) * (NCH * HW)
                                   + ((t & 255) << 10) + tid * 4;
        float4 vals[NCH];
        #pragma unroll
        for (int c = 0; c < NCH; ++c)
            vals[c] = *(const float4*)(base + (size_t)c * HW);
        const int p0 = t * 1024 + tid * 4;
        const int4 lab4 = *(const int4*)(labels + p0);
        const int labs[4] = {lab4.x, lab4.y, lab4.z, lab4.w};

        #pragma unroll
        for (int j = 0; j < 4; ++j) {
            float m = -__builtin_inff(), picked = 0.f;
            #pragma unroll
            for (int c = 0; c < NCH; ++c) {
                float x = (j == 0) ? vals[c].x : (j == 1) ? vals[c].y
                        : (j == 2) ? vals[c].z : vals[c].w;
                m = fmaxf(m, x);
                if (c == labs[j]) picked = x;
            }
            float s = 0.f;
            #pragma unroll
            for (int c = 0; c < NCH; ++c) {
                float x = (j == 0) ? vals[c].x : (j == 1) ? vals[c].y
                        : (j == 2) ? vals[c].z : vals[c].w;
                s += __expf(x - m);
            }
            float loss = m + logf(s) - picked;      // >= 0 (s >= 1)
            bool valid = (labs[j] != IGN);
            if (valid) {
                lls[((k << 2) + j) * 256 + tid] = loss;
                atomicAdd(&lh[__float_as_uint(loss) >> 21], 1u);
                if (loss > THRESH_F) { lsum += loss; lcnt++; }
            } else {
                lls[((k << 2) + j) * 256 + tid] = -__builtin_inff();
            }
        }
    }
    // branch-1 block reduction -> per-block slot (no global atomics)
    #pragma unroll
    for (int o = 32; o > 0; o >>= 1) { lsum += __shfl_down(lsum, o); lcnt += __shfl_down(lcnt, o); }
    if ((tid & 63) == 0) { s_sumw[tid >> 6] = lsum; s_cntw[tid >> 6] = lcnt; }
    __syncthreads();
    if (tid == 0) {
        psum[bid] = s_sumw[0] + s_sumw[1] + s_sumw[2] + s_sumw[3];
        pcnt[bid] = s_cntw[0] + s_cntw[1] + s_cntw[2] + s_cntw[3];
    }
    for (int i = tid; i < 2048; i += 256) { unsigned int c = lh[i]; if (c) atomicAdd(&hist1[i], c); }

    __threadfence();
    grid.sync();

    // ---------------- phase 2: hist2 within B1 + sum above B1 --------------
    select_from_hist(hist1, 2048, KSEL, res, lh, ssum);
    const int B1 = res[0];
    for (int i = tid; i < 2048; i += 256) lh[i] = 0u;
    __syncthreads();
    float h1s = 0.f;
    #pragma unroll
    for (int q = 0; q < NPASS * 4; ++q) {
        float lv = lls[q * 256 + tid];
        unsigned int w = __float_as_uint(lv);
        if (!(w & 0x80000000u)) {
            int b1 = (int)(w >> 21);
            if (b1 == B1)      atomicAdd(&lh[(w >> 10) & 0x7FFu], 1u);
            else if (b1 > B1)  h1s += lv;
        }
    }
    #pragma unroll
    for (int o = 32; o > 0; o >>= 1) h1s += __shfl_down(h1s, o);
    if ((tid & 63) == 0) s_sumw[tid >> 6] = h1s;
    __syncthreads();
    if (tid == 0) ghi1[bid] = (double)(s_sumw[0] + s_sumw[1] + s_sumw[2] + s_sumw[3]);
    for (int i = tid; i < 2048; i += 256) { unsigned int c = lh[i]; if (c) atomicAdd(&hist2[i], c); }

    __threadfence();
    grid.sync();

    // ---------------- phase 3: hist3 within (B1,B2) + sum above B2 ---------
    select_from_hist(hist1, 2048, KSEL, res, lh, ssum);
    const int B1b = res[0];
    const unsigned int a1 = (unsigned int)res[1];
    select_from_hist(hist2, 2048, KSEL - a1, res, lh, ssum);
    const int B2 = res[0];
    for (int i = tid; i < 1024; i += 256) lh[i] = 0u;
    __syncthreads();
    float h2s = 0.f;
    #pragma unroll
    for (int q = 0; q < NPASS * 4; ++q) {
        float lv = lls[q * 256 + tid];
        unsigned int w = __float_as_uint(lv);
        if (!(w & 0x80000000u) && (int)(w >> 21) == B1b) {
            int b2 = (int)((w >> 10) & 0x7FFu);
            if (b2 == B2)      atomicAdd(&lh[w & 0x3FFu], 1u);
            else if (b2 > B2)  h2s += lv;
        }
    }
    #pragma unroll
    for (int o = 32; o > 0; o >>= 1) h2s += __shfl_down(h2s, o);
    if ((tid & 63) == 0) s_sumw[tid >> 6] = h2s;
    __syncthreads();
    if (tid == 0) ghi2[bid] = (double)(s_sumw[0] + s_sumw[1] + s_sumw[2] + s_sumw[3]);
    for (int i = tid; i < 1024; i += 256) { unsigned int c = lh[i]; if (c) atomicAdd(&hist3[i], c); }

    __threadfence();
    grid.sync();

    // ---------------- phase 4: block 0 finishes ----------------------------
    if (bid != 0) return;

    double my_sum = 0.0, my_h1 = 0.0, my_h2 = 0.0;
    unsigned long long my_cnt = 0ull;
    #pragma unroll
    for (int i = 0; i < 2; ++i) {
        my_sum += (double)psum[tid * 2 + i];
        my_cnt += (unsigned long long)pcnt[tid * 2 + i];
        my_h1  += ghi1[tid * 2 + i];
        my_h2  += ghi2[tid * 2 + i];
    }
    #pragma unroll
    for (int o = 32; o > 0; o >>= 1) {
        my_sum += __shfl_down(my_sum, o);
        my_cnt += __shfl_down(my_cnt, o);
        my_h1  += __shfl_down(my_h1, o);
        my_h2  += __shfl_down(my_h2, o);
    }
    if ((tid & 63) == 0) {
        sdbl[tid >> 6]       = my_sum;
        sdbl[4 + (tid >> 6)] = my_h1;
        sdbl[8 + (tid >> 6)] = my_h2;
        s_cntw[tid >> 6]     = (unsigned int)my_cnt;
    }
    __syncthreads();
    const double tot_s  = sdbl[0] + sdbl[1] + sdbl[2] + sdbl[3];
    const double tot_h1 = sdbl[4] + sdbl[5] + sdbl[6] + sdbl[7];
    const double tot_h2 = sdbl[8] + sdbl[9] + sdbl[10] + sdbl[11];
    const unsigned int tot_c = s_cntw[0] + s_cntw[1] + s_cntw[2] + s_cntw[3];
    __syncthreads();

    select_from_hist(hist1, 2048, KSEL, res, lh, ssum);
    const int fB1 = res[0];
    const unsigned int fa1 = (unsigned int)res[1];
    select_from_hist(hist2, 2048, KSEL - fa1, res, lh, ssum);
    const int fB2 = res[0];
    const unsigned int fa2 = (unsigned int)res[1];
    const unsigned int need3 = KSEL - fa1 - fa2;
    const unsigned int hibits = ((unsigned int)fB1 << 21) | ((unsigned int)fB2 << 10);

    // level-3 scan with value-weighted suffix sums (lh = h3)
    for (int i = tid; i < 1024; i += 256) lh[i] = hist3[i];
    __syncthreads();
    unsigned int cp = 0; double sp = 0.0;
    #pragma unroll
    for (int i = 0; i < 4; ++i) {
        int b = tid * 4 + i;
        unsigned int c = lh[b];
        cp += c;
        sp += (double)c * (double)__uint_as_float(hibits | (unsigned int)b);
    }
    ssum[tid] = cp; sdbl[tid] = sp;
    __syncthreads();
    for (int off = 1; off < 256; off <<= 1) {
        unsigned int ca = (tid + off < 256) ? ssum[tid + off] : 0u;
        double       sa = (tid + off < 256) ? sdbl[tid + off] : 0.0;
        __syncthreads();
        ssum[tid] += ca; sdbl[tid] += sa;
        __syncthreads();
    }
    __shared__ int r_l;
    __shared__ unsigned int r_above;
    __shared__ double r_sum3;
    unsigned int Sme   = ssum[tid];
    unsigned int Snext = (tid < 255) ? ssum[tid + 1] : 0u;
    double       Wnext = (tid < 255) ? sdbl[tid + 1] : 0.0;
    if (Sme >= need3 && Snext < need3) {
        unsigned int above = Snext;
        double sum3 = Wnext;
        int l = tid * 4;
        for (int b = tid * 4 + 3; b >= tid * 4; --b) {
            unsigned int c = lh[b];
            if (above + c >= need3) { l = b; break; }
            above += c;
            sum3 += (double)c * (double)__uint_as_float(hibits | (unsigned int)b);
        }
        r_l = l; r_above = above; r_sum3 = sum3;
    }
    if (tid == 0 && ssum[0] < need3) { r_l = 0; r_above = 0; r_sum3 = 0.0; }
    __syncthreads();

    if (tid == 0) {
        float v = __uint_as_float(hibits | (unsigned int)r_l);   // exact kth value
        unsigned long long cnt_above = (unsigned long long)fa1 + fa2 + r_above;
        double sum_above = tot_h1 + tot_h2 + r_sum3;
        double mean_top = (sum_above + (double)(KSEL - cnt_above) * (double)v) / (double)KSEL;
        double result;
        if (v > THRESH_F) {
            result = tot_s / (double)(tot_c > 0u ? tot_c : 1u);
        } else {
            result = mean_top;
        }
        out[0] = (float)result;
    }
}

extern "C" void kernel_launch(void* const* d_in, const int* in_sizes, int n_in,
                              void* d_out, int out_size, void* d_ws, size_t ws_size,
                              hipStream_t stream)
{
    const float* logits = (const float*)d_in[0];
    const int*   labels = (const int*)d_in[1];
    float* out = (float*)d_out;

    // workspace layout (bytes)
    unsigned int* hist1 = (unsigned int*)d_ws;                    //     0 ..  8191
    unsigned int* hist2 = hist1 + 2048;                           //  8192 .. 16383
    unsigned int* hist3 = hist2 + 2048;                           // 16384 .. 20479
    float*        psum  = (float*)((char*)d_ws + 20480);          //  512 f32
    unsigned int* pcnt  = (unsigned int*)((char*)d_ws + 24576);   //  512 u32
    double*       ghi1  = (double*)((char*)d_ws + 28672);         //  512 f64
    double*       ghi2  = (double*)((char*)d_ws + 32768);         //  512 f64

    hipMemsetAsync(d_ws, 0, 20480, stream);   // zero the three histograms

    void* args[] = { (void*)&logits, (void*)&labels,
                     (void*)&hist1, (void*)&hist2, (void*)&hist3,
                     (void*)&psum, (void*)&pcnt, (void*)&ghi1, (void*)&ghi2,
                     (void*)&out };
    hipLaunchCooperativeKernel((const void*)k_mega, dim3(GBLK), dim3(256),
                               args, 0, stream);
}